// Round 2
// baseline (1394.164 us; speedup 1.0000x reference)
//
#include <hip/hip_runtime.h>

#define NB 8
#define NN 4096
#define MM 4096
#define CC 256

typedef unsigned short u16;
typedef __attribute__((ext_vector_type(2))) unsigned short u16x2;
typedef __attribute__((ext_vector_type(4))) unsigned short u16x4;
typedef __attribute__((ext_vector_type(8))) short s16x8;
typedef __attribute__((ext_vector_type(4))) float f32x4;

#define INV_EPS 33.333333333333336f
#define POWER   0.94339622641509435f   /* 0.5/(0.5+0.03) */
#define PROB    (1.0f/4096.0f)

static __device__ __forceinline__ float bf2f(u16 h) {
    union { unsigned int u; float f; } v;
    v.u = ((unsigned int)h) << 16;
    return v.f;
}
static __device__ __forceinline__ u16 f2bf(float f) {
    union { float f; unsigned int u; } v;
    v.f = f;
    unsigned int u = v.u;
    u += 0x7fffu + ((u >> 16) & 1u);   // round-to-nearest-even
    return (u16)(u >> 16);
}

// ---------------------------------------------------------------------------
// L2-normalize rows of (rows x 256) fp32 -> bf16. One wave per row.
// grid = rows/4, block = 256 (4 waves).
// ---------------------------------------------------------------------------
__global__ __launch_bounds__(256) void norm_kernel(const float* __restrict__ src,
                                                   u16* __restrict__ dst)
{
    const int t = threadIdx.x, w = t >> 6, lane = t & 63;
    const size_t row = (size_t)blockIdx.x * 4 + w;
    const float* sp = src + row * CC + lane * 4;
    f32x4 v = *(const f32x4*)sp;
    float s = v.x * v.x + v.y * v.y + v.z * v.z + v.w * v.w;
    for (int o = 32; o > 0; o >>= 1) s += __shfl_xor(s, o);
    float rn = rsqrtf(s + 1e-8f);
    u16x4 o4;
    o4.x = f2bf(v.x * rn); o4.y = f2bf(v.y * rn);
    o4.z = f2bf(v.z * rn); o4.w = f2bf(v.w * rn);
    *(u16x4*)(dst + row * CC + lane * 4) = o4;
}

// ---------------------------------------------------------------------------
// Strip GEMM: Ks[ls][r][c] = exp((f1s[ls][r]·f2s[ls][c] - 1)/eps), bf16 out.
// 128x128 tile, 4 waves, mfma_f32_16x16x32_bf16.
// A-operand = f2 rows (m-dim = c) so each lane's 4 acc regs are 4
// consecutive c -> 8B stores. grid (MM/128, NN/128, cnt).
// ---------------------------------------------------------------------------
#define LDSS 72   /* 64 + 8 pad, in u16 units */

__global__ __launch_bounds__(256, 2) void gemm_exp_kernel(
    const u16* __restrict__ f1s, const u16* __restrict__ f2s,
    u16* __restrict__ Ks)
{
    const int t = threadIdx.x;
    const int w = t >> 6, lane = t & 63;
    const int quad = lane >> 4, l15 = lane & 15;
    const int bx = blockIdx.x;   // c-tile (f2 rows)
    const int by = blockIdx.y;   // r-tile (f1 rows)
    const int ls = blockIdx.z;   // local batch in strip

    __shared__ u16 As[128 * LDSS];   // f2 tile (A-operand)
    __shared__ u16 Bs[128 * LDSS];   // f1 tile (B-operand)

    const u16* f2base = f2s + ((size_t)ls * MM + (size_t)bx * 128) * CC;
    const u16* f1base = f1s + ((size_t)ls * NN + (size_t)by * 128) * CC;

    f32x4 acc[4][4];
#pragma unroll
    for (int i = 0; i < 4; ++i)
#pragma unroll
        for (int j = 0; j < 4; ++j) acc[i][j] = (f32x4){0.f, 0.f, 0.f, 0.f};

    const int g_r = t >> 3;          // 0..31
    const int g_c = (t & 7) << 3;    // 0,8,..,56

    for (int kt = 0; kt < 4; ++kt) {
        const int k0 = kt * 64;
        __syncthreads();
#pragma unroll
        for (int i = 0; i < 4; ++i) {
            const int row = g_r + i * 32;
            s16x8 va = *(const s16x8*)(f2base + (size_t)row * CC + k0 + g_c);
            s16x8 vb = *(const s16x8*)(f1base + (size_t)row * CC + k0 + g_c);
            *(s16x8*)&As[row * LDSS + g_c] = va;
            *(s16x8*)&Bs[row * LDSS + g_c] = vb;
        }
        __syncthreads();
#pragma unroll
        for (int s = 0; s < 2; ++s) {
            s16x8 af[4], bfr[4];
#pragma unroll
            for (int i = 0; i < 4; ++i)
                af[i] = *(const s16x8*)&As[((w & 1) * 64 + i * 16 + l15) * LDSS + s * 32 + quad * 8];
#pragma unroll
            for (int j = 0; j < 4; ++j)
                bfr[j] = *(const s16x8*)&Bs[((w >> 1) * 64 + j * 16 + l15) * LDSS + s * 32 + quad * 8];
#pragma unroll
            for (int i = 0; i < 4; ++i)
#pragma unroll
                for (int j = 0; j < 4; ++j)
                    acc[i][j] = __builtin_amdgcn_mfma_f32_16x16x32_bf16(af[i], bfr[j], acc[i][j], 0, 0, 0);
        }
    }

    u16* kb = Ks + (size_t)ls * NN * MM;
    const int rbase = by * 128 + (w >> 1) * 64 + l15;
    const int cbase = bx * 128 + (w & 1) * 64 + quad * 4;
#pragma unroll
    for (int j = 0; j < 4; ++j) {
        const int r = rbase + j * 16;
#pragma unroll
        for (int i = 0; i < 4; ++i) {
            const int c = cbase + i * 16;
            f32x4 v = acc[i][j];
            u16x4 o;
            o.x = f2bf(expf((v.x - 1.f) * INV_EPS));
            o.y = f2bf(expf((v.y - 1.f) * INV_EPS));
            o.z = f2bf(expf((v.z - 1.f) * INV_EPS));
            o.w = f2bf(expf((v.w - 1.f) * INV_EPS));
            *(u16x4*)&kb[(size_t)r * MM + c] = o;
        }
    }
}

// ---------------------------------------------------------------------------
// init per strip: a = 1/N, KTa = 0.  grid = cnt*NN/256.
// ---------------------------------------------------------------------------
__global__ __launch_bounds__(256) void init_kernel(float* __restrict__ a,
                                                   float* __restrict__ KTa)
{
    const int t = blockIdx.x * 256 + threadIdx.x;
    a[t] = PROB;
    KTa[t] = 0.f;
}

// ---------------------------------------------------------------------------
// KTa[ls][m] += sum_n Ks[ls][n][m] * a[ls][n]  (column pass; atomic partials)
// grid (MM/512, NN/256, cnt), 256 threads; each thread owns 2 columns.
// ---------------------------------------------------------------------------
__global__ __launch_bounds__(256) void kta_kernel(const u16* __restrict__ Ks,
                                                  const float* __restrict__ a,
                                                  float* __restrict__ KTa)
{
    const int t = threadIdx.x;
    const int ls = blockIdx.z;
    const int m = blockIdx.x * 512 + t * 2;
    const int n0 = blockIdx.y * 256;
    const u16* kp = Ks + (size_t)ls * NN * MM + (size_t)n0 * MM + m;
    const float* ap = a + ls * NN + n0;
    float s0 = 0.f, s1 = 0.f;
#pragma unroll 8
    for (int n = 0; n < 256; ++n) {
        u16x2 kk = *(const u16x2*)kp;
        kp += MM;
        const float av = ap[n];
        s0 += bf2f(kk.x) * av;
        s1 += bf2f(kk.y) * av;
    }
    atomicAdd(&KTa[ls * MM + m], s0);
    atomicAdd(&KTa[ls * MM + m + 1], s1);
}

// b = (prob2 / (KTa + 1e-8))^power ; re-zero KTa for next iteration
__global__ __launch_bounds__(256) void bfin_kernel(float* __restrict__ KTa,
                                                   float* __restrict__ bvec)
{
    const int t = blockIdx.x * 256 + threadIdx.x;
    const float v = KTa[t];
    KTa[t] = 0.f;
    bvec[t] = powf(PROB / (v + 1e-8f), POWER);
}

// ---------------------------------------------------------------------------
// Row pass + fused a-update: a[ls][n] = (prob1/(sum_m K b + 1e-8))^power
// wave per row; grid = cnt*NN/4, 256 threads = 4 waves.
// ---------------------------------------------------------------------------
__global__ __launch_bounds__(256) void kb_a_kernel(const u16* __restrict__ Ks,
                                                   const float* __restrict__ bvec,
                                                   float* __restrict__ a)
{
    const int t = threadIdx.x, w = t >> 6, lane = t & 63;
    const int R = blockIdx.x * 4 + w;
    const int ls = R >> 12, n = R & 4095;
    const u16* kp = Ks + ((size_t)ls * NN + n) * MM;
    const float* bp = bvec + ls * MM;
    float s = 0.f;
#pragma unroll 4
    for (int pass = 0; pass < 16; ++pass) {
        const int m = pass * 256 + lane * 4;
        u16x4 k4 = *(const u16x4*)(kp + m);
        f32x4 b4 = *(const f32x4*)(bp + m);
        s += bf2f(k4.x) * b4.x + bf2f(k4.y) * b4.y
           + bf2f(k4.z) * b4.z + bf2f(k4.w) * b4.w;
    }
    for (int o = 32; o > 0; o >>= 1) s += __shfl_xor(s, o);
    if (lane == 0) a[ls * NN + n] = powf(PROB / (s + 1e-8f), POWER);
}

// bp4[ls][m] = { b, b*p2x, b*p2y, b*p2z }   grid = cnt*MM/256
__global__ __launch_bounds__(256) void bp4_kernel(const float* __restrict__ bvec,
                                                  const float* __restrict__ p2,
                                                  float* __restrict__ bp4)
{
    const int t = blockIdx.x * 256 + threadIdx.x;
    const float bv = bvec[t];
    const float x = p2[(size_t)t * 3 + 0];
    const float y = p2[(size_t)t * 3 + 1];
    const float z = p2[(size_t)t * 3 + 2];
    f32x4 o = {bv, bv * x, bv * y, bv * z};
    *(f32x4*)&bp4[(size_t)t * 4] = o;
}

// ---------------------------------------------------------------------------
// Final pass: per row n, y_k = sum_m K[n][m]*bp4[m][k]; s0 = Kb (final b),
// so a is derived here (saves a whole Kb pass). Writes
// wc4 = { corr_x, corr_y, corr_z, weight }. grid = cnt*NN/4.
// ---------------------------------------------------------------------------
__global__ __launch_bounds__(256) void final_kernel(const u16* __restrict__ Ks,
                                                    const float* __restrict__ bp4,
                                                    float* __restrict__ wc4)
{
    const int t = threadIdx.x, w = t >> 6, lane = t & 63;
    const int R = blockIdx.x * 4 + w;
    const int ls = R >> 12, n = R & 4095;
    const u16* kp = Ks + ((size_t)ls * NN + n) * MM;
    const float* pp = bp4 + (size_t)ls * MM * 4;
    float s0 = 0.f, s1 = 0.f, s2 = 0.f, s3 = 0.f;
#pragma unroll 2
    for (int pass = 0; pass < 16; ++pass) {
        const int m = pass * 256 + lane * 4;
        u16x4 k4 = *(const u16x4*)(kp + m);
#pragma unroll
        for (int e = 0; e < 4; ++e) {
            const float kv = bf2f(((const u16*)&k4)[e]);
            f32x4 p = *(const f32x4*)&pp[(size_t)(m + e) * 4];
            s0 += kv * p.x; s1 += kv * p.y; s2 += kv * p.z; s3 += kv * p.w;
        }
    }
    for (int o = 32; o > 0; o >>= 1) {
        s0 += __shfl_xor(s0, o); s1 += __shfl_xor(s1, o);
        s2 += __shfl_xor(s2, o); s3 += __shfl_xor(s3, o);
    }
    if (lane == 0) {
        const float av = powf(PROB / (s0 + 1e-8f), POWER);
        const float wgt = av * s0;
        const float inv = 1.f / (wgt + 1e-8f);
        f32x4 o = {av * s1 * inv, av * s2 * inv, av * s3 * inv, wgt};
        *(f32x4*)&wc4[((size_t)ls * NN + n) * 4] = o;
    }
}

// ---------------------------------------------------------------------------
// Weighted Kabsch per batch: fp64 reduction + one-sided Jacobi SVD (3x3)
// grid = cnt; p1/out pre-offset by strip base.
// ---------------------------------------------------------------------------
__global__ __launch_bounds__(256) void kabsch_kernel(const float* __restrict__ wc4,
                                                     const float* __restrict__ p1,
                                                     float* __restrict__ out)
{
    const int b = blockIdx.x;
    const int t = threadIdx.x, w = t >> 6, lane = t & 63;
    double acc[16];
#pragma unroll
    for (int k = 0; k < 16; ++k) acc[k] = 0.0;

    for (int n = t; n < NN; n += 256) {
        const float* wp = wc4 + ((size_t)b * NN + n) * 4;
        const float cx = wp[0], cy = wp[1], cz = wp[2], wgt = wp[3];
        const float* pp = p1 + ((size_t)b * NN + n) * 3;
        const double px = pp[0], py = pp[1], pz = pp[2];
        const double wd = wgt;
        const double wcx = wd * cx, wcy = wd * cy, wcz = wd * cz;
        acc[0] += wd;
        acc[1] += wd * px; acc[2] += wd * py; acc[3] += wd * pz;
        acc[4] += wcx;     acc[5] += wcy;     acc[6] += wcz;
        acc[7]  += px * wcx; acc[8]  += px * wcy; acc[9]  += px * wcz;
        acc[10] += py * wcx; acc[11] += py * wcy; acc[12] += py * wcz;
        acc[13] += pz * wcx; acc[14] += pz * wcy; acc[15] += pz * wcz;
    }

    __shared__ double red[4][16];
#pragma unroll
    for (int k = 0; k < 16; ++k) {
        double v = acc[k];
        for (int o = 32; o > 0; o >>= 1) v += __shfl_xor(v, o);
        acc[k] = v;
    }
    if (lane == 0)
        for (int k = 0; k < 16; ++k) red[w][k] = acc[k];
    __syncthreads();

    if (t == 0) {
        double S[16];
        for (int k = 0; k < 16; ++k)
            S[k] = red[0][k] + red[1][k] + red[2][k] + red[3][k];
        const double denom = S[0] + 1e-5;
        const double sfrac = S[0] / denom;
        double ca[3] = {S[1] / denom, S[2] / denom, S[3] / denom};
        double cb[3] = {S[4] / denom, S[5] / denom, S[6] / denom};
        double A[3][3], V[3][3];
        for (int i = 0; i < 3; ++i)
            for (int j = 0; j < 3; ++j) {
                A[i][j] = S[7 + i * 3 + j] / denom - (2.0 - sfrac) * ca[i] * cb[j];
                V[i][j] = (i == j) ? 1.0 : 0.0;
            }
        // one-sided Jacobi: orthogonalize columns of A, accumulate V
        for (int sweep = 0; sweep < 20; ++sweep) {
            const int PP[3] = {0, 0, 1}, QQ[3] = {1, 2, 2};
            for (int r = 0; r < 3; ++r) {
                const int p = PP[r], q = QQ[r];
                double app = 0, aqq = 0, apq = 0;
                for (int i = 0; i < 3; ++i) {
                    app += A[i][p] * A[i][p];
                    aqq += A[i][q] * A[i][q];
                    apq += A[i][p] * A[i][q];
                }
                if (fabs(apq) < 1e-14 * (app + aqq) + 1e-300) continue;
                const double th = 0.5 * atan2(2.0 * apq, app - aqq);
                const double c = cos(th), sn = sin(th);
                for (int i = 0; i < 3; ++i) {
                    double x = A[i][p], y = A[i][q];
                    A[i][p] = c * x + sn * y; A[i][q] = -sn * x + c * y;
                    x = V[i][p]; y = V[i][q];
                    V[i][p] = c * x + sn * y; V[i][q] = -sn * x + c * y;
                }
            }
        }
        double sv[3];
        for (int j = 0; j < 3; ++j)
            sv[j] = sqrt(A[0][j] * A[0][j] + A[1][j] * A[1][j] + A[2][j] * A[2][j]);
        int idx[3] = {0, 1, 2};
        if (sv[idx[0]] < sv[idx[1]]) { int x = idx[0]; idx[0] = idx[1]; idx[1] = x; }
        if (sv[idx[0]] < sv[idx[2]]) { int x = idx[0]; idx[0] = idx[2]; idx[2] = x; }
        if (sv[idx[1]] < sv[idx[2]]) { int x = idx[1]; idx[1] = idx[2]; idx[2] = x; }
        double U[3][3], Vs[3][3];
        for (int j = 0; j < 3; ++j) {
            const int jj = idx[j];
            const double inv = 1.0 / fmax(sv[jj], 1e-300);
            for (int i = 0; i < 3; ++i) {
                U[i][j] = A[i][jj] * inv;
                Vs[i][j] = V[i][jj];
            }
        }
        double R[3][3];
        for (int i = 0; i < 3; ++i)
            for (int j = 0; j < 3; ++j)
                R[i][j] = Vs[i][0] * U[j][0] + Vs[i][1] * U[j][1] + Vs[i][2] * U[j][2];
        const double det = R[0][0] * (R[1][1] * R[2][2] - R[1][2] * R[2][1])
                         - R[0][1] * (R[1][0] * R[2][2] - R[1][2] * R[2][0])
                         + R[0][2] * (R[1][0] * R[2][1] - R[1][1] * R[2][0]);
        if (det < 0.0) {
            for (int i = 0; i < 3; ++i) Vs[i][2] = -Vs[i][2];
            for (int i = 0; i < 3; ++i)
                for (int j = 0; j < 3; ++j)
                    R[i][j] = Vs[i][0] * U[j][0] + Vs[i][1] * U[j][1] + Vs[i][2] * U[j][2];
        }
        double tr[3];
        for (int i = 0; i < 3; ++i)
            tr[i] = cb[i] - (R[i][0] * ca[0] + R[i][1] * ca[1] + R[i][2] * ca[2]);
        float* o = out + b * 12;
        for (int i = 0; i < 3; ++i) {
            o[i * 4 + 0] = (float)R[i][0];
            o[i * 4 + 1] = (float)R[i][1];
            o[i * 4 + 2] = (float)R[i][2];
            o[i * 4 + 3] = (float)tr[i];
        }
    }
}

// ---------------------------------------------------------------------------
extern "C" void kernel_launch(void* const* d_in, const int* in_sizes, int n_in,
                              void* d_out, int out_size, void* d_ws, size_t ws_size,
                              hipStream_t stream) {
    const float* f1 = (const float*)d_in[0];
    const float* f2 = (const float*)d_in[1];
    const float* p1 = (const float*)d_in[2];
    const float* p2 = (const float*)d_in[3];
    float* out = (float*)d_out;

    // --- per-batch workspace footprint (bytes), 256B-aligned regions ---
    const size_t AL = 256;
    const size_t szK   = (size_t)NN * MM * 2;          // 33.55 MB bf16 K
    const size_t szF1  = (size_t)NN * CC * 2;          // 2 MB
    const size_t szF2  = (size_t)MM * CC * 2;          // 2 MB
    const size_t szA   = (size_t)NN * 4;
    const size_t szB   = (size_t)MM * 4;
    const size_t szKTa = (size_t)MM * 4;
    const size_t szBp4 = (size_t)MM * 16;
    const size_t szWc4 = (size_t)NN * 16;
    const size_t per_batch = szK + szF1 + szF2 + szA + szB + szKTa + szBp4 + szWc4 + 8 * AL;

    int NS = (int)(ws_size / per_batch);
    if (NS > NB) NS = NB;
    if (NS < 1) NS = 1;                                // last-resort: hope it fits

    char* base = (char*)d_ws;
    size_t off = 0;
    auto carve = [&](size_t bytes) -> char* {
        char* p = base + off;
        off += (bytes + AL - 1) & ~(AL - 1);
        return p;
    };
    u16*   Ks   = (u16*)  carve((size_t)NS * szK);
    u16*   f1s  = (u16*)  carve((size_t)NS * szF1);
    u16*   f2s  = (u16*)  carve((size_t)NS * szF2);
    float* avec = (float*)carve((size_t)NS * szA);
    float* bvec = (float*)carve((size_t)NS * szB);
    float* KTa  = (float*)carve((size_t)NS * szKTa);
    float* bp4  = (float*)carve((size_t)NS * szBp4);
    float* wc4  = (float*)carve((size_t)NS * szWc4);

    for (int b0 = 0; b0 < NB; b0 += NS) {
        const int cnt = (NB - b0 < NS) ? (NB - b0) : NS;

        norm_kernel<<<cnt * NN / 4, 256, 0, stream>>>(f1 + (size_t)b0 * NN * CC, f1s);
        norm_kernel<<<cnt * MM / 4, 256, 0, stream>>>(f2 + (size_t)b0 * MM * CC, f2s);
        gemm_exp_kernel<<<dim3(MM / 128, NN / 128, cnt), 256, 0, stream>>>(f1s, f2s, Ks);
        init_kernel<<<cnt * NN / 256, 256, 0, stream>>>(avec, KTa);

        for (int it = 0; it < 10; ++it) {
            kta_kernel<<<dim3(MM / 512, NN / 256, cnt), 256, 0, stream>>>(Ks, avec, KTa);
            bfin_kernel<<<cnt * MM / 256, 256, 0, stream>>>(KTa, bvec);
            if (it < 9)
                kb_a_kernel<<<cnt * NN / 4, 256, 0, stream>>>(Ks, bvec, avec);
        }

        bp4_kernel<<<cnt * MM / 256, 256, 0, stream>>>(bvec, p2 + (size_t)b0 * MM * 3, bp4);
        final_kernel<<<cnt * NN / 4, 256, 0, stream>>>(Ks, bp4, wc4);
        kabsch_kernel<<<cnt, 256, 0, stream>>>(wc4, p1 + (size_t)b0 * NN * 3, out + (size_t)b0 * 12);
    }

    (void)in_sizes; (void)n_in; (void)out_size;
}